// Round 5
// baseline (7521.781 us; speedup 1.0000x reference)
//
#include <hip/hip_runtime.h>
#include <hip/hip_cooperative_groups.h>

namespace cg = cooperative_groups;

// Problem constants (match reference)
namespace {
constexpr int B = 16, N = 256, L = 4, H = 128, V = 512, OV = 1000, MAX_STEPS = 48;
constexpr int Z = 4 * H;   // 512 gate width
constexpr int BN = B * N;  // 4096 rows
constexpr int PADK = 132;  // padded LDS row stride (ushorts) to break bank aliasing
constexpr int SB = BN * H; // 524288 floats per state tensor
}

typedef __attribute__((ext_vector_type(8))) short short8;  // 8 bf16 (4 VGPRs)
typedef __attribute__((ext_vector_type(4))) float f32x4;   // MFMA C/D

union F8 {
    short8 s;
    uint4 u;
    uint2 h[2];
};

__device__ __forceinline__ float sigf(float x) { return 1.0f / (1.0f + __expf(-x)); }
__device__ __forceinline__ float tanh_f(float x) { return 1.0f - 2.0f / (__expf(2.0f * x) + 1.0f); }

__device__ __forceinline__ unsigned short bf16_rne(float x) {
    unsigned u = __float_as_uint(x);
    return (unsigned short)((u + 0x7fffu + ((u >> 16) & 1u)) >> 16);
}
__device__ __forceinline__ void split2(float x, unsigned short& hi, unsigned short& lo) {
    hi = bf16_rne(x);
    const float hf = __uint_as_float(((unsigned)hi) << 16);
    lo = bf16_rne(x - hf);
}

// ---------------------------------------------------------------------------
// tokz[v, :] = emb[v, :] @ Wi0 + b0   (512 x 512, K=128) -- fp32, computed once.
// ---------------------------------------------------------------------------
__global__ __launch_bounds__(256) void k_tokz(const float* __restrict__ emb,
                                              const float* __restrict__ Wi0,
                                              const float* __restrict__ b0,
                                              float* __restrict__ tokz) {
    __shared__ float lds_a[16 * 128];
    float4* l4 = (float4*)lds_a;
    const int tid = threadIdx.x;
    const int c = tid & 127, rg = tid >> 7;
    const int row0 = blockIdx.x * 16;
    {
        const float4* a4 = (const float4*)emb;
        l4[tid] = a4[row0 * 32 + tid];
        l4[tid + 256] = a4[row0 * 32 + tid + 256];
    }
    __syncthreads();
    float acc[8][4];
    {
        float bq[4];
#pragma unroll
        for (int q = 0; q < 4; q++) bq[q] = b0[c + q * 128];
#pragma unroll
        for (int i = 0; i < 8; i++)
#pragma unroll
            for (int q = 0; q < 4; q++) acc[i][q] = bq[q];
    }
    for (int k4 = 0; k4 < 32; k4++) {
        float4 a[8];
#pragma unroll
        for (int i = 0; i < 8; i++) a[i] = l4[(rg * 8 + i) * 32 + k4];
#pragma unroll
        for (int j = 0; j < 4; j++) {
            const int k = k4 * 4 + j;
            const float* wr = Wi0 + k * Z + c;
            const float w0 = wr[0], w1 = wr[128], w2 = wr[256], w3 = wr[384];
#pragma unroll
            for (int i = 0; i < 8; i++) {
                const float av = (j == 0) ? a[i].x : (j == 1) ? a[i].y : (j == 2) ? a[i].z : a[i].w;
                acc[i][0] += av * w0;
                acc[i][1] += av * w1;
                acc[i][2] += av * w2;
                acc[i][3] += av * w3;
            }
        }
    }
#pragma unroll
    for (int i = 0; i < 8; i++) {
        const int row = row0 + rg * 8 + i;
#pragma unroll
        for (int q = 0; q < 4; q++) tokz[row * Z + c + q * 128] = acc[i][q];
    }
}

// ---------------------------------------------------------------------------
// Pack weights into MFMA B-fragment order, split into bf16 hi/lo.
// Entry (mat,q,w,ks): 64 lanes x 8 bf16; lane lp elem j holds
//   W[k][col],  k = ks*32 + ((j&4)?16:0) + (lp>>4)*4 + (j&3),
//               col = q*128 + w*16 + (lp&15).
// Same (g,j)->k formula is used for A fragments, so the true HW k-order
// cancels (dot over k is permutation-invariant).
// ---------------------------------------------------------------------------
__global__ __launch_bounds__(256) void k_pack(const float* __restrict__ Wh0,
                                              const float* __restrict__ Wi1,
                                              const float* __restrict__ Wh1,
                                              unsigned short* __restrict__ WPhi,
                                              unsigned short* __restrict__ WPlo) {
    const int gid = blockIdx.x * 256 + threadIdx.x;
    const int lp = gid & 63;
    const int ks = (gid >> 6) & 3;
    const int w = (gid >> 8) & 7;
    const int q = (gid >> 11) & 3;
    const int split = (gid >> 13) & 1;
    const int mat = gid >> 14;  // 0..2
    const float* W = (mat == 0) ? Wh0 : (mat == 1) ? Wi1 : Wh1;
    const int g = lp >> 4, li = lp & 15;
    const int col = q * 128 + w * 16 + li;
    const int e = ((mat * 4 + q) * 8 + w) * 4 + ks;
    unsigned short* dst = (split ? WPlo : WPhi) + (size_t)e * 512 + lp * 8;
#pragma unroll
    for (int j = 0; j < 8; j++) {
        const int k = ks * 32 + ((j & 4) ? 16 : 0) + g * 4 + (j & 3);
        const float x = W[k * Z + col];
        const unsigned short hi = bf16_rne(x);
        unsigned short v = hi;
        if (split) {
            const float hf = __uint_as_float(((unsigned)hi) << 16);
            v = bf16_rne(x - hf);
        }
        dst[j] = v;
    }
}

// ---------------------------------------------------------------------------
// Build per-example CSR of dest <- (src, branch-flag). Runs once.
// ---------------------------------------------------------------------------
__global__ __launch_bounds__(256) void k_csr(const int* __restrict__ tix,
                                             const int* __restrict__ fix,
                                             int* __restrict__ off,
                                             int* __restrict__ ent) {
    const int b = blockIdx.x;
    const int m = threadIdx.x;
    __shared__ int cnt[N];
    __shared__ int wsum[4];
    cnt[m] = 0;
    __syncthreads();
    const int ti = tix[b * N + m];
    const int fi = fix[b * N + m];
    atomicAdd(&cnt[ti], 1);
    atomicAdd(&cnt[fi], 1);
    __syncthreads();
    const int v = cnt[m];
    const int lane = m & 63, w = m >> 6;
    int sc = v;  // inclusive scan within wave
#pragma unroll
    for (int o = 1; o < 64; o <<= 1) {
        const int t = __shfl_up(sc, o);
        if (lane >= o) sc += t;
    }
    if (lane == 63) wsum[w] = sc;
    __syncthreads();
    int add = 0;
    for (int i = 0; i < w; i++) add += wsum[i];
    const int base = sc - v + add;  // exclusive prefix
    off[b * (N + 1) + m] = base;
    if (m == N - 1) off[b * (N + 1) + N] = base + v;
    __syncthreads();
    cnt[m] = base;  // reuse as scatter cursor
    __syncthreads();
    const int p1 = atomicAdd(&cnt[ti], 1);
    ent[b * 2 * N + p1] = (m << 1);
    const int p2 = atomicAdd(&cnt[fi], 1);
    ent[b * 2 * N + p2] = (m << 1) | 1;
}

// ---------------------------------------------------------------------------
// Persistent cooperative kernel: all 48 steps. 256 blocks x 512 threads,
// block bx owns rows [bx*16, bx*16+16). cur states + ip live in LDS for the
// whole run; only work states + wt/wf (ping-ponged) cross blocks via global.
// One grid.sync per step (scan -> agg); agg->next-scan is block-local.
// ---------------------------------------------------------------------------
__global__ __launch_bounds__(512, 2) void k_persist(
    const unsigned short* __restrict__ WPhi, const unsigned short* __restrict__ WPlo,
    const float* __restrict__ b1, const float* __restrict__ tokz,
    const int* __restrict__ data, const float* __restrict__ bw,
    const float* __restrict__ bb,
    float* __restrict__ work0, float* __restrict__ work1,
    float* __restrict__ wtwf0, float* __restrict__ wtwf1,
    const int* __restrict__ csr_off, const int* __restrict__ csr_ent,
    const int* __restrict__ start, const int* __restrict__ exiti,
    const int* __restrict__ steps, const float* __restrict__ ow,
    const float* __restrict__ obias, float* __restrict__ h1fin,
    float* __restrict__ out) {
    const int bx = blockIdx.x;
    const int b = bx >> 4;
    const int nbase = (bx & 15) * 16;  // example-local first node of this block
    const int row0 = bx * 16;          // global row base
    const int tid = threadIdx.x;
    const int w = tid >> 6;
    const int l = tid & 63;
    const int g = l >> 4, li = l & 15;
    const int ch = w * 16 + li;  // hidden col 0..127
    cg::grid_group grid = cg::this_grid();

    __shared__ float cur[4][16][132];  // c0,h0,c1,h1 fp32 (padded stride)
    __shared__ unsigned short h0hi[16 * PADK], h0lo[16 * PADK];
    __shared__ unsigned short h1hi[16 * PADK], h1lo[16 * PADK];
    __shared__ float red[16][8][2];
    __shared__ float ip_l[16];

    const int mysteps = steps[b];
    const int ex = exiti[b];
    int rex = -1;  // which of my 4 local rows is the exit row (-1 none)
    if ((ex >> 4) == (bx & 15) && ((ex & 15) >> 2) == g) rex = ex & 3;

    for (int i = tid; i < 4 * 16 * 132; i += 512) ((float*)cur)[i] = 0.f;
    if (tid < 16) ip_l[tid] = (nbase + tid == start[b]) ? 1.0f : 0.0f;

    float b1v[4];
#pragma unroll
    for (int q = 0; q < 4; q++) b1v[q] = b1[q * 128 + ch];
    float2 bwv[4];
#pragma unroll
    for (int x = 0; x < 4; x++) bwv[x] = ((const float2*)bw)[x * 128 + ch];
    const float bb0 = bb[0], bb1 = bb[1];
    __syncthreads();

    for (int s = 0; s < MAX_STEPS; s++) {
        const bool active = (s < mysteps);  // block-uniform
        float* Wk = (s & 1) ? work1 : work0;
        float* wtp = (s & 1) ? wtwf1 : wtwf0;
        float* wfp = wtp + BN;

        // ==================== phase A: scan + branch softmax ================
        if (active) {
            float c0[4], h0[4], c1[4], h1[4];
#pragma unroll
            for (int r = 0; r < 4; r++) {
                const int rl = g * 4 + r;
                c0[r] = cur[0][rl][ch];
                h0[r] = cur[1][rl][ch];
                c1[r] = cur[2][rl][ch];
                h1[r] = cur[3][rl][ch];
            }
            float sc0 = 0, sh0 = 0, sc1 = 0, sh1 = 0;
            if (rex >= 0) { sc0 = c0[rex]; sh0 = h0[rex]; sc1 = c1[rex]; sh1 = h1[rex]; }
            // initial h -> LDS (bf16 hi/lo)
#pragma unroll
            for (int r = 0; r < 4; r++) {
                unsigned short hi, lo;
                split2(h0[r], hi, lo);
                h0hi[(g * 4 + r) * PADK + ch] = hi;
                h0lo[(g * 4 + r) * PADK + ch] = lo;
                split2(h1[r], hi, lo);
                h1hi[(g * 4 + r) * PADK + ch] = hi;
                h1lo[(g * 4 + r) * PADK + ch] = lo;
            }
            __syncthreads();

#pragma unroll 1
            for (int t = 0; t < L; t++) {
                // ---- layer 0: z = tokz[data[:,t]] + h0 @ Wh0
                f32x4 acc[4];
                {
                    int tok[4];
#pragma unroll
                    for (int r = 0; r < 4; r++) tok[r] = data[(row0 + g * 4 + r) * L + t];
#pragma unroll
                    for (int q = 0; q < 4; q++)
#pragma unroll
                        for (int r = 0; r < 4; r++) acc[q][r] = tokz[tok[r] * Z + q * 128 + ch];
                }
#pragma unroll
                for (int ks = 0; ks < 4; ks++) {
                    F8 ahi, alo;
                    const int ab = li * PADK + ks * 32 + g * 4;
                    ahi.h[0] = *(const uint2*)&h0hi[ab];
                    ahi.h[1] = *(const uint2*)&h0hi[ab + 16];
                    alo.h[0] = *(const uint2*)&h0lo[ab];
                    alo.h[1] = *(const uint2*)&h0lo[ab + 16];
#pragma unroll
                    for (int q = 0; q < 4; q++) {
                        F8 bhi, blo;
                        const int e = ((0 * 4 + q) * 8 + w) * 4 + ks;
                        bhi.u = *(const uint4*)(WPhi + (size_t)e * 512 + l * 8);
                        blo.u = *(const uint4*)(WPlo + (size_t)e * 512 + l * 8);
                        acc[q] = __builtin_amdgcn_mfma_f32_16x16x32_bf16(ahi.s, bhi.s, acc[q], 0, 0, 0);
                        acc[q] = __builtin_amdgcn_mfma_f32_16x16x32_bf16(ahi.s, blo.s, acc[q], 0, 0, 0);
                        acc[q] = __builtin_amdgcn_mfma_f32_16x16x32_bf16(alo.s, bhi.s, acc[q], 0, 0, 0);
                    }
                }
#pragma unroll
                for (int r = 0; r < 4; r++) {
                    const float cn = sigf(acc[1][r]) * c0[r] + sigf(acc[0][r]) * tanh_f(acc[2][r]);
                    c0[r] = cn;
                    h0[r] = sigf(acc[3][r]) * tanh_f(cn);
                }
                __syncthreads();
#pragma unroll
                for (int r = 0; r < 4; r++) {
                    unsigned short hi, lo;
                    split2(h0[r], hi, lo);
                    h0hi[(g * 4 + r) * PADK + ch] = hi;
                    h0lo[(g * 4 + r) * PADK + ch] = lo;
                }
                __syncthreads();
                // ---- layer 1: z = h0new @ Wi1 + h1 @ Wh1 + b1
#pragma unroll
                for (int q = 0; q < 4; q++) {
                    const float bv = b1v[q];
                    acc[q][0] = bv; acc[q][1] = bv; acc[q][2] = bv; acc[q][3] = bv;
                }
#pragma unroll
                for (int ks = 0; ks < 4; ks++) {
                    F8 a0hi, a0lo, a1hi, a1lo;
                    const int ab = li * PADK + ks * 32 + g * 4;
                    a0hi.h[0] = *(const uint2*)&h0hi[ab];
                    a0hi.h[1] = *(const uint2*)&h0hi[ab + 16];
                    a0lo.h[0] = *(const uint2*)&h0lo[ab];
                    a0lo.h[1] = *(const uint2*)&h0lo[ab + 16];
                    a1hi.h[0] = *(const uint2*)&h1hi[ab];
                    a1hi.h[1] = *(const uint2*)&h1hi[ab + 16];
                    a1lo.h[0] = *(const uint2*)&h1lo[ab];
                    a1lo.h[1] = *(const uint2*)&h1lo[ab + 16];
#pragma unroll
                    for (int q = 0; q < 4; q++) {
                        F8 b1hi, b1lo, b2hi, b2lo;
                        const int e1 = ((1 * 4 + q) * 8 + w) * 4 + ks;
                        const int e2 = ((2 * 4 + q) * 8 + w) * 4 + ks;
                        b1hi.u = *(const uint4*)(WPhi + (size_t)e1 * 512 + l * 8);
                        b1lo.u = *(const uint4*)(WPlo + (size_t)e1 * 512 + l * 8);
                        b2hi.u = *(const uint4*)(WPhi + (size_t)e2 * 512 + l * 8);
                        b2lo.u = *(const uint4*)(WPlo + (size_t)e2 * 512 + l * 8);
                        acc[q] = __builtin_amdgcn_mfma_f32_16x16x32_bf16(a0hi.s, b1hi.s, acc[q], 0, 0, 0);
                        acc[q] = __builtin_amdgcn_mfma_f32_16x16x32_bf16(a0hi.s, b1lo.s, acc[q], 0, 0, 0);
                        acc[q] = __builtin_amdgcn_mfma_f32_16x16x32_bf16(a0lo.s, b1hi.s, acc[q], 0, 0, 0);
                        acc[q] = __builtin_amdgcn_mfma_f32_16x16x32_bf16(a1hi.s, b2hi.s, acc[q], 0, 0, 0);
                        acc[q] = __builtin_amdgcn_mfma_f32_16x16x32_bf16(a1hi.s, b2lo.s, acc[q], 0, 0, 0);
                        acc[q] = __builtin_amdgcn_mfma_f32_16x16x32_bf16(a1lo.s, b2hi.s, acc[q], 0, 0, 0);
                    }
                }
#pragma unroll
                for (int r = 0; r < 4; r++) {
                    const float cn = sigf(acc[1][r]) * c1[r] + sigf(acc[0][r]) * tanh_f(acc[2][r]);
                    c1[r] = cn;
                    h1[r] = sigf(acc[3][r]) * tanh_f(cn);
                }
                __syncthreads();
#pragma unroll
                for (int r = 0; r < 4; r++) {
                    unsigned short hi, lo;
                    split2(h1[r], hi, lo);
                    h1hi[(g * 4 + r) * PADK + ch] = hi;
                    h1lo[(g * 4 + r) * PADK + ch] = lo;
                }
                __syncthreads();
            }

            // exit-row patch: contrib[exit] = cur[exit] (saved before scan)
            if (rex >= 0) { c0[rex] = sc0; h0[rex] = sh0; c1[rex] = sc1; h1[rex] = sh1; }
            // store work states (read cross-block in phase B)
#pragma unroll
            for (int r = 0; r < 4; r++) {
                const int off = (row0 + g * 4 + r) * H + ch;
                Wk[off] = c0[r];
                Wk[SB + off] = h0[r];
                Wk[2 * SB + off] = c1[r];
                Wk[3 * SB + off] = h1[r];
            }
            // branch softmax: l = concat(c0,h0,c1,h1) @ bw + bb, * ip
            float l0p[4], l1p[4];
#pragma unroll
            for (int r = 0; r < 4; r++) {
                l0p[r] = c0[r] * bwv[0].x + h0[r] * bwv[1].x + c1[r] * bwv[2].x + h1[r] * bwv[3].x;
                l1p[r] = c0[r] * bwv[0].y + h0[r] * bwv[1].y + c1[r] * bwv[2].y + h1[r] * bwv[3].y;
            }
#pragma unroll
            for (int off = 8; off > 0; off >>= 1)
#pragma unroll
                for (int r = 0; r < 4; r++) {
                    l0p[r] += __shfl_xor(l0p[r], off);
                    l1p[r] += __shfl_xor(l1p[r], off);
                }
            if (li == 0)
#pragma unroll
                for (int r = 0; r < 4; r++) {
                    red[g * 4 + r][w][0] = l0p[r];
                    red[g * 4 + r][w][1] = l1p[r];
                }
            __syncthreads();
            if (tid < 16) {
                float l0 = bb0, l1 = bb1;
#pragma unroll
                for (int ww = 0; ww < 8; ww++) {
                    l0 += red[tid][ww][0];
                    l1 += red[tid][ww][1];
                }
                const float m = fmaxf(l0, l1);
                const float e0 = __expf(l0 - m), e1 = __expf(l1 - m);
                const float inv = 1.0f / (e0 + e1);
                const float ipv = ip_l[tid];
                wtp[row0 + tid] = e0 * inv * ipv;
                wfp[row0 + tid] = e1 * inv * ipv;
            }
        }

        grid.sync();  // work + wt/wf visible to all blocks

        // ==================== phase B: ip redistribution + aggregation ======
        if (active) {
            const int lane = l;
#pragma unroll 1
            for (int rr = 0; rr < 2; rr++) {
                const int nloc = w * 2 + rr;
                const int n = nbase + nloc;
                const int beg = csr_off[b * (N + 1) + n];
                const int end = csr_off[b * (N + 1) + n + 1];
                float a00 = 0, a01 = 0, a10 = 0, a11 = 0, a20 = 0, a21 = 0, a30 = 0, a31 = 0;
                float ipacc = 0.f;
                for (int e = beg; e < end; e++) {
                    const int pe = csr_ent[b * 2 * N + e];
                    const int m = pe >> 1;
                    const float wgt = (pe & 1) ? wfp[b * N + m] : wtp[b * N + m];
                    ipacc += wgt;
                    const int rb = (b * N + m) * H;
                    a00 += Wk[rb + lane] * wgt;
                    a01 += Wk[rb + lane + 64] * wgt;
                    a10 += Wk[SB + rb + lane] * wgt;
                    a11 += Wk[SB + rb + lane + 64] * wgt;
                    a20 += Wk[2 * SB + rb + lane] * wgt;
                    a21 += Wk[2 * SB + rb + lane + 64] * wgt;
                    a30 += Wk[3 * SB + rb + lane] * wgt;
                    a31 += Wk[3 * SB + rb + lane + 64] * wgt;
                }
                const float dn = 1.0f / (ipacc + 1e-7f);
                cur[0][nloc][lane] = a00 * dn;
                cur[0][nloc][lane + 64] = a01 * dn;
                cur[1][nloc][lane] = a10 * dn;
                cur[1][nloc][lane + 64] = a11 * dn;
                cur[2][nloc][lane] = a20 * dn;
                cur[2][nloc][lane + 64] = a21 * dn;
                cur[3][nloc][lane] = a30 * dn;
                cur[3][nloc][lane + 64] = a31 * dn;
                if (lane == 0) ip_l[nloc] = ipacc;
            }
        }
        __syncthreads();  // cur LDS ready for next phase A (block-local)
    }

    // ==================== epilogue: out[b] = h1[exit] @ ow + obias ==========
    if ((ex >> 4) == (bx & 15) && tid < 128) h1fin[b * H + tid] = cur[3][ex & 15][tid];
    grid.sync();
    if (bx < B) {
        const int bb_ = bx;
        for (int v = tid; v < OV; v += 512) {
            float acc = obias[v];
            for (int d = 0; d < H; d++) acc += h1fin[bb_ * H + d] * ow[d * OV + v];
            out[bb_ * OV + v] = acc;
        }
    }
}

// ---------------------------------------------------------------------------
extern "C" void kernel_launch(void* const* d_in, const int* in_sizes, int n_in,
                              void* d_out, int out_size, void* d_ws, size_t ws_size,
                              hipStream_t stream) {
    (void)in_sizes; (void)n_in; (void)out_size;
    const int* data = (const int*)d_in[0];
    const int* tix = (const int*)d_in[1];
    const int* fix = (const int*)d_in[2];
    const int* start = (const int*)d_in[3];
    const int* exiti = (const int*)d_in[4];
    const int* steps = (const int*)d_in[5];
    const float* emb = (const float*)d_in[6];
    const float* Wi0 = (const float*)d_in[7];
    const float* b0 = (const float*)d_in[9];
    const float* Wh0 = (const float*)d_in[8];
    const float* Wi1 = (const float*)d_in[10];
    const float* Wh1 = (const float*)d_in[11];
    const float* b1 = (const float*)d_in[12];
    const float* bw = (const float*)d_in[13];
    const float* bb = (const float*)d_in[14];
    const float* ow = (const float*)d_in[15];
    const float* obias = (const float*)d_in[16];
    float* out = (float*)d_out;

    // workspace layout (floats)
    float* ws = (float*)d_ws;
    float* tokz = ws;                       // V*Z
    float* work0 = tokz + (size_t)V * Z;    // 4*SB
    float* work1 = work0 + 4 * (size_t)SB;  // 4*SB
    float* wtwf0 = work1 + 4 * (size_t)SB;  // 2*BN
    float* wtwf1 = wtwf0 + 2 * BN;          // 2*BN
    float* h1fin = wtwf1 + 2 * BN;          // B*H
    unsigned short* WPhi = (unsigned short*)(h1fin + B * H);  // 3*65536
    unsigned short* WPlo = WPhi + 3 * 65536;                  // 3*65536
    int* csr_off = (int*)(WPlo + 3 * 65536);                  // B*(N+1)
    int* csr_ent = csr_off + B * (N + 1);                     // B*2N
    const size_t need = ((size_t)V * Z + 8 * (size_t)SB + 4 * BN + B * H) * 4 +
                        6 * 65536 * 2 + (B * (N + 1) + 2 * B * N) * 4;
    if (ws_size < need) return;

    k_tokz<<<V / 16, 256, 0, stream>>>(emb, Wi0, b0, tokz);
    k_pack<<<192, 256, 0, stream>>>(Wh0, Wi1, Wh1, WPhi, WPlo);
    k_csr<<<B, 256, 0, stream>>>(tix, fix, csr_off, csr_ent);

    void* args[] = {(void*)&WPhi, (void*)&WPlo, (void*)&b1, (void*)&tokz,
                    (void*)&data, (void*)&bw, (void*)&bb,
                    (void*)&work0, (void*)&work1, (void*)&wtwf0, (void*)&wtwf1,
                    (void*)&csr_off, (void*)&csr_ent,
                    (void*)&start, (void*)&exiti, (void*)&steps,
                    (void*)&ow, (void*)&obias, (void*)&h1fin, (void*)&out};
    hipLaunchCooperativeKernel((const void*)k_persist, dim3(BN / 16), dim3(512),
                               args, 0, stream);
}